// Round 4
// baseline (105.559 us; speedup 1.0000x reference)
//
#include <hip/hip_runtime.h>
#include <stdint.h>

// Problem constants: B=32, N=1024, C=64, G=64
//
// R19 = R18 + XCD-locality mapping + full-tile prefetch distance.
// Cost model from R15/R17/R18 deltas: dur_us = floor(~55, harness dispatches,
// fixed) + proj(~8) + attn(~36). The 44us fillBufferAligned ws-poisons are
// OUTSIDE dur_us (R17 arithmetic proves it). Lever = attn.
// attn's 36us >> issue-work model (<10us) -> latency holes:
//  (1) blocks of one batch round-robin over 8 XCDs -> batch's 256KB K/V image
//      first-touched into 8 different L2s from a fill-churned L3 (~600cy);
//  (2) V(t) issued at tile top, used ~300cy later; K(t+1) issued after QK --
//      neither covers L3-class latency.
// Fix: blk -> (b,qt) mapping with all 16 blocks of a batch on one XCD
// (blk%8 = const); XCD x serves ranks {x,15-x,31-x,16+x} (XCD-balanced,
// halves paired heavy+light). proj uses the SAME placement (now computes
// sched) so images are written and read on the same XCD -> L2-warm.
// Loop restructured: preload K(0),V(0); issue K(t+1),V(t+1) at tile top
// (~550cy cover). Arithmetic verbatim -> bit-identical output.
// Fallback: if ws_size < 12MB, launch the unmodified R15 kernel.

typedef __attribute__((ext_vector_type(4))) float    floatx4;
typedef __attribute__((ext_vector_type(8))) _Float16 halfx8;

static __device__ __forceinline__ unsigned short f2h(float f) {
    union { _Float16 h; unsigned short u; } v; v.h = (_Float16)f;
    return v.u;
}
static __device__ __forceinline__ float h2f(unsigned short u) {
    union { unsigned short u; _Float16 h; } v; v.u = u;
    return (float)v.h;
}

#define MFMA16(a, bb, c) __builtin_amdgcn_mfma_f32_16x16x32_f16((a), (bb), (c), 0, 0, 0)

// blk (0..511) -> (rank, qt) with blk%8 = XCD-constant per batch.
// XCD x hosts ranks {x, 15-x, 31-x, 16+x}; qt = (blk>>3)&15.
static __device__ __forceinline__ int rank_of_blk(int blk) {
    int x = blk & 7;
    int s = blk >> 7;            // (blk>>3)>>4 : 0..3
    return (s == 0) ? x : (s == 1) ? 15 - x : (s == 2) ? 31 - x : 16 + x;
}

// ============================================================================
// Pass 1: projections. Block handles x rows (b*16+qt)*64 .. +63 where b is
// sched[rank_of_blk] (same placement as pass 2 -> same-XCD L2 reuse).
// Writes three 8KB pre-swizzled fp16 images per (b,qt):
//   Q/K image: img[row*64 + ((c8 ^ (row&7))*8) + j] = P[row][c8*8+j]
//   V image  : img[g*64  + ((kc8 ^ (g&7))*8) + j]   = V[kc8*8+j][g]   (V^T)
// ============================================================================
__global__ __launch_bounds__(256, 2) void proj_kernel(
    const float* __restrict__ x,
    const float* __restrict__ Wq, const float* __restrict__ bq,
    const float* __restrict__ Wk, const float* __restrict__ bk,
    const float* __restrict__ Wv, const float* __restrict__ bv,
    const int* __restrict__ valid_len,
    unsigned short* __restrict__ qimg,
    unsigned short* __restrict__ kimg,
    unsigned short* __restrict__ vimg)
{
    __shared__ __align__(16) unsigned short sm[24576];   // 48 KB
    __shared__ int sched[32];
    const int XH = 0, XL = 4096, WQH = 8192, WQL = 12288, WKH = 16384, WVH = 20480;

    const int tid  = threadIdx.x;
    const int blk  = blockIdx.x;          // 0..511
    const int lane = tid & 63;
    const int w    = tid >> 6;
    const int l15  = lane & 15;
    const int quad = lane >> 4;
    const int rl   = lane >> 2;
    const int c8a  = 2 * (lane & 3);
    const int c8b  = c8a + 1;
    const int sidx_a = rl * 64 + ((c8a ^ (rl & 7)) * 8);
    const int sidx_b = rl * 64 + ((c8b ^ (rl & 7)) * 8);

    if (tid < 32) {
        int vlb = valid_len[tid];
        int ntb = (vlb == 0) ? 16 : ((vlb + 63) >> 6);
        int rank = 0;
        for (int b2 = 0; b2 < 32; ++b2) {
            int vl2 = valid_len[b2];
            int nt2 = (vl2 == 0) ? 16 : ((vl2 + 63) >> 6);
            rank += (nt2 > ntb) || (nt2 == ntb && b2 < tid);
        }
        sched[rank] = tid;
    }
    __syncthreads();

    const int b  = sched[rank_of_blk(blk)];
    const int qt = (blk >> 3) & 15;
    const int tile = b * 16 + qt;

    // ---- stage x (hi + lo residual), wave-private 16-row slices ----
    {
        const float* xrow = x + (size_t)(tile * 64 + w * 16) * 64;
#pragma unroll
        for (int i = 0; i < 2; ++i) {
            int c8   = (i == 0) ? c8a : c8b;
            int sidx = (i == 0) ? sidx_a : sidx_b;
            const float4* gp = (const float4*)(xrow + rl * 64 + c8 * 8);
            float4 f0 = gp[0], f1 = gp[1];
            float fv[8] = { f0.x, f0.y, f0.z, f0.w, f1.x, f1.y, f1.z, f1.w };
            __align__(16) unsigned short thi[8], tlo[8];
#pragma unroll
            for (int j = 0; j < 8; ++j) {
                unsigned short hi = f2h(fv[j]);
                thi[j] = hi;
                tlo[j] = f2h(fv[j] - h2f(hi));
            }
            *(uint4*)&sm[XH + w * 1024 + sidx] = *(uint4*)thi;
            *(uint4*)&sm[XL + w * 1024 + sidx] = *(uint4*)tlo;
        }
    }
    // ---- stage Wq(hi,lo), Wk, Wv  ([g][c] transposed, XOR-swizzled) ----
    {
        int g = tid & 63, ci = tid >> 6;
#pragma unroll
        for (int j = 0; j < 16; ++j) {
            int c = ci * 16 + j;
            int idx = g * 64 + (((c >> 3) ^ (g & 7)) * 8) + (c & 7);
            float fq = Wq[c * 64 + g];
            unsigned short qhi = f2h(fq);
            sm[WQH + idx] = qhi;
            sm[WQL + idx] = f2h(fq - h2f(qhi));
            sm[WKH + idx] = f2h(Wk[c * 64 + g]);
            sm[WVH + idx] = f2h(Wv[c * 64 + g]);
        }
    }
    __syncthreads();

    const int fidx0 = l15 * 64 + (((0 + quad) ^ (l15 & 7)) * 8);
    const int fidx1 = l15 * 64 + (((4 + quad) ^ (l15 & 7)) * 8);
    halfx8 ah0 = *(const halfx8*)&sm[XH + w * 1024 + fidx0];
    halfx8 ah1 = *(const halfx8*)&sm[XH + w * 1024 + fidx1];
    halfx8 al0 = *(const halfx8*)&sm[XL + w * 1024 + fidx0];
    halfx8 al1 = *(const halfx8*)&sm[XL + w * 1024 + fidx1];

    floatx4 vacc[4];
#pragma unroll
    for (int gs = 0; gs < 4; ++gs) {
        int brow = gs * 16 + l15;
        int b0 = brow * 64 + (((0 + quad) ^ (brow & 7)) * 8);
        int b1 = brow * 64 + (((4 + quad) ^ (brow & 7)) * 8);
        halfx8 bh0 = *(const halfx8*)&sm[WQH + b0];
        halfx8 bh1 = *(const halfx8*)&sm[WQH + b1];
        halfx8 bl0 = *(const halfx8*)&sm[WQL + b0];
        halfx8 bl1 = *(const halfx8*)&sm[WQL + b1];
        halfx8 wk0 = *(const halfx8*)&sm[WKH + b0];
        halfx8 wk1 = *(const halfx8*)&sm[WKH + b1];
        halfx8 wv0 = *(const halfx8*)&sm[WVH + b0];
        halfx8 wv1 = *(const halfx8*)&sm[WVH + b1];

        float bbq = bq[gs * 16 + l15];
        floatx4 qa = { bbq, bbq, bbq, bbq };
        qa = MFMA16(ah0, bh0, qa);
        qa = MFMA16(ah1, bh1, qa);
        qa = MFMA16(ah0, bl0, qa);
        qa = MFMA16(ah1, bl1, qa);
        qa = MFMA16(al0, bh0, qa);
        qa = MFMA16(al1, bh1, qa);

        float bbk = bk[gs * 16 + l15];
        float bbv = bv[gs * 16 + l15];
        floatx4 ka = { bbk, bbk, bbk, bbk };
        floatx4 va = { bbv, bbv, bbv, bbv };
        ka = MFMA16(ah0, wk0, ka);
        ka = MFMA16(ah1, wk1, ka);
        va = MFMA16(ah0, wv0, va);
        va = MFMA16(ah1, wv1, va);
        vacc[gs] = va;

        // Q image -> XH (own-wave rows), K image -> XL (own-wave rows).
        int c8 = gs * 2 + (l15 >> 3);
#pragma unroll
        for (int r = 0; r < 4; ++r) {
            int row = w * 16 + quad * 4 + r;
            int idx = row * 64 + ((c8 ^ (row & 7)) * 8) + (l15 & 7);
            sm[XH + idx] = f2h(qa[r]);
            sm[XL + idx] = f2h(ka[r]);
        }
    }
    __syncthreads();   // all waves done reading Wq-hi -> WQH reusable as V image
#pragma unroll
    for (int gs = 0; gs < 4; ++gs) {
        int g = gs * 16 + l15;
#pragma unroll
        for (int r = 0; r < 4; ++r) {
            int key = w * 16 + quad * 4 + r;
            sm[WQH + g * 64 + (((key >> 3) ^ (g & 7)) * 8) + (key & 7)] = f2h(vacc[gs][r]);
        }
    }
    __syncthreads();

    // ---- cooperative copy: 3 x 8KB images -> global workspace ----
    {
        const size_t tb = (size_t)tile * 4096;   // shorts per image
#pragma unroll
        for (int i = 0; i < 2; ++i) {
            int ci = i * 256 + tid;             // 512 x 16B chunks per image
            *(uint4*)&qimg[tb + ci * 8] = *(const uint4*)&sm[XH  + ci * 8];
            *(uint4*)&kimg[tb + ci * 8] = *(const uint4*)&sm[XL  + ci * 8];
            *(uint4*)&vimg[tb + ci * 8] = *(const uint4*)&sm[WQH + ci * 8];
        }
    }
}

// ============================================================================
// Pass 2: barrier-free attention, same-XCD L2-warm K/V images, 1-full-tile
// prefetch distance for both K and V.
// ============================================================================
__global__ __launch_bounds__(256, 2) void attn_kernel(
    const unsigned short* __restrict__ qimg,
    const unsigned short* __restrict__ kimg,
    const unsigned short* __restrict__ vimg,
    const int* __restrict__ valid_len, float* __restrict__ out)
{
    __shared__ __align__(16) unsigned short psmem[4096];  // 8 KB: 4 waves x 2KB
    __shared__ int sched[32];

    const int tid  = threadIdx.x;
    const int blk  = blockIdx.x;          // 0..511
    const int lane = tid & 63;
    const int w    = tid >> 6;
    const int l15  = lane & 15;
    const int quad = lane >> 4;

    if (tid < 32) {
        int vlb = valid_len[tid];
        int ntb = (vlb == 0) ? 16 : ((vlb + 63) >> 6);
        int rank = 0;
        for (int b2 = 0; b2 < 32; ++b2) {
            int vl2 = valid_len[b2];
            int nt2 = (vl2 == 0) ? 16 : ((vl2 + 63) >> 6);
            rank += (nt2 > ntb) || (nt2 == ntb && b2 < tid);
        }
        sched[rank] = tid;
    }
    __syncthreads();   // the ONLY block-wide barrier

    const int b    = sched[rank_of_blk(blk)];
    const int qt   = (blk >> 3) & 15;
    const int row0 = b * 1024 + qt * 64;

    const int vl    = valid_len[b];
    const int nt    = (vl == 0) ? 16 : ((vl + 63) >> 6);
    const int fullt = vl >> 6;

    // ---- Q fragments straight from the global image ----
    const int arow = w * 16 + l15;
    const unsigned short* qb = qimg + (size_t)(b * 16 + qt) * 4096;
    halfx8 aq0 = *(const halfx8*)&qb[arow * 64 + (((0 + quad) ^ (arow & 7)) * 8)];
    halfx8 aq1 = *(const halfx8*)&qb[arow * 64 + (((4 + quad) ^ (arow & 7)) * 8)];

    // ---- fragment byte indices within a 4096-short tile image ----
    int idx0[4], idx1[4];
#pragma unroll
    for (int sub = 0; sub < 4; ++sub) {
        int r = sub * 16 + l15;
        idx0[sub] = r * 64 + (((0 + quad) ^ (r & 7)) * 8);
        idx1[sub] = r * 64 + (((4 + quad) ^ (r & 7)) * 8);
    }

    const unsigned short* kt_base = kimg + (size_t)b * 65536;
    const unsigned short* vt_base = vimg + (size_t)b * 65536;

    float m_r[4]    = { -INFINITY, -INFINITY, -INFINITY, -INFINITY };
    float l_lane[4] = { 0.f, 0.f, 0.f, 0.f };
    floatx4 o[4] = { {0,0,0,0}, {0,0,0,0}, {0,0,0,0}, {0,0,0,0} };

    unsigned short* psw = &psmem[w * 1024];

    // preload K(0), V(0)
    halfx8 kf0[4], kf1[4], vf0[4], vf1[4];
#pragma unroll
    for (int sub = 0; sub < 4; ++sub) {
        kf0[sub] = *(const halfx8*)&kt_base[idx0[sub]];
        kf1[sub] = *(const halfx8*)&kt_base[idx1[sub]];
        vf0[sub] = *(const halfx8*)&vt_base[idx0[sub]];
        vf1[sub] = *(const halfx8*)&vt_base[idx1[sub]];
    }

    for (int t = 0; t < nt; ++t) {
        // issue K(t+1) AND V(t+1) at tile top: ~full tile (~550cy) of cover
        const bool pre = (t + 1) < nt;
        halfx8 nk0[4], nk1[4], nv0[4], nv1[4];
        if (pre) {
            const unsigned short* ktn = kt_base + (size_t)(t + 1) * 4096;
            const unsigned short* vtn = vt_base + (size_t)(t + 1) * 4096;
#pragma unroll
            for (int sub = 0; sub < 4; ++sub) {
                nk0[sub] = *(const halfx8*)&ktn[idx0[sub]];
                nk1[sub] = *(const halfx8*)&ktn[idx1[sub]];
                nv0[sub] = *(const halfx8*)&vtn[idx0[sub]];
                nv1[sub] = *(const halfx8*)&vtn[idx1[sub]];
            }
        }

        // ---- scores (consume K(t)) ----
        floatx4 s[4];
#pragma unroll
        for (int sub = 0; sub < 4; ++sub) {
            floatx4 acc = { 0, 0, 0, 0 };
            acc = MFMA16(aq0, kf0[sub], acc);
            acc = MFMA16(aq1, kf1[sub], acc);
            s[sub] = acc;
        }

        if (t >= fullt) {
#pragma unroll
            for (int sub = 0; sub < 4; ++sub) {
                int key = t * 64 + sub * 16 + l15;
                if (key >= vl) { s[sub][0] = -1e6f; s[sub][1] = -1e6f; s[sub][2] = -1e6f; s[sub][3] = -1e6f; }
            }
        }

        // ---- online softmax (verbatim R15) ----
        float p[4][4];
        float alpha[4];
#pragma unroll
        for (int r = 0; r < 4; ++r) {
            float mx = fmaxf(fmaxf(s[0][r], s[1][r]), fmaxf(s[2][r], s[3][r]));
#pragma unroll
            for (int off = 1; off < 16; off <<= 1)
                mx = fmaxf(mx, __shfl_xor(mx, off, 64));
            float mnew = fmaxf(m_r[r], mx);
            alpha[r] = __expf(m_r[r] - mnew);
            float psum = 0.f;
#pragma unroll
            for (int sub = 0; sub < 4; ++sub) {
                float pv = __expf(s[sub][r] - mnew);
                p[sub][r] = pv;
                psum += pv;
            }
            l_lane[r] = l_lane[r] * alpha[r] + psum;
            m_r[r] = mnew;
        }
#pragma unroll
        for (int gs = 0; gs < 4; ++gs) {
            o[gs][0] *= alpha[0]; o[gs][1] *= alpha[1];
            o[gs][2] *= alpha[2]; o[gs][3] *= alpha[3];
        }

        // ---- P staging (wave-private LDS) + PV ----
#pragma unroll
        for (int sub = 0; sub < 4; ++sub) {
            int c8 = sub * 2 + (l15 >> 3);
#pragma unroll
            for (int r = 0; r < 4; ++r) {
                int row = quad * 4 + r;
                psw[row * 64 + ((c8 ^ (row & 7)) * 8) + (l15 & 7)] = f2h(p[sub][r]);
            }
        }
        halfx8 ap0 = *(const halfx8*)&psw[l15 * 64 + (((0 + quad) ^ (l15 & 7)) * 8)];
        halfx8 ap1 = *(const halfx8*)&psw[l15 * 64 + (((4 + quad) ^ (l15 & 7)) * 8)];

#pragma unroll
        for (int gs = 0; gs < 4; ++gs) {
            o[gs] = MFMA16(ap0, vf0[gs], o[gs]);
            o[gs] = MFMA16(ap1, vf1[gs], o[gs]);
        }

        if (pre) {
#pragma unroll
            for (int sub = 0; sub < 4; ++sub) {
                kf0[sub] = nk0[sub];
                kf1[sub] = nk1[sub];
                vf0[sub] = nv0[sub];
                vf1[sub] = nv1[sub];
            }
        }
    }

    // ---- final 16-lane sum butterfly, store ----
    float l[4];
#pragma unroll
    for (int r = 0; r < 4; ++r) {
        float ss = l_lane[r];
#pragma unroll
        for (int off = 1; off < 16; off <<= 1)
            ss += __shfl_xor(ss, off, 64);
        l[r] = ss;
    }
#pragma unroll
    for (int gs = 0; gs < 4; ++gs) {
#pragma unroll
        for (int r = 0; r < 4; ++r) {
            int row = row0 + w * 16 + quad * 4 + r;
            out[row * 64 + gs * 16 + l15] = o[gs][r] / l[r];
        }
    }
}

// ============================================================================
// Fallback: unmodified R15 single-pass kernel (used if ws_size < 12 MB)
// ============================================================================
__global__ __launch_bounds__(256, 2) void fused_attn_fallback(
    const float* __restrict__ x,
    const float* __restrict__ Wq, const float* __restrict__ bq,
    const float* __restrict__ Wk, const float* __restrict__ bk,
    const float* __restrict__ Wv, const float* __restrict__ bv,
    const int* __restrict__ valid_len, float* __restrict__ out)
{
    __shared__ __align__(16) unsigned short smem[28672];   // 56 KB
    __shared__ int sched[32];

    const int Q_OFF = 0, XH_OFF = 4096, KL0_OFF = 8192, KL1_OFF = 12288,
              VS0_OFF = 16384, VS1_OFF = 20480, PS_OFF = 24576;

    const int tid  = threadIdx.x;
    const int blk  = blockIdx.x;
    const int lane = tid & 63;
    const int w    = tid >> 6;
    const int l15  = lane & 15;
    const int quad = lane >> 4;

    if (tid < 32) {
        int vlb = valid_len[tid];
        int ntb = (vlb == 0) ? 16 : ((vlb + 63) >> 6);
        int rank = 0;
        for (int b2 = 0; b2 < 32; ++b2) {
            int vl2 = valid_len[b2];
            int nt2 = (vl2 == 0) ? 16 : ((vl2 + 63) >> 6);
            rank += (nt2 > ntb) || (nt2 == ntb && b2 < tid);
        }
        sched[rank] = tid;
    }
    __syncthreads();

    const int hv   = (blk < 256);
    const int b    = hv ? sched[blk >> 4] : sched[31 - ((blk - 256) >> 4)];
    const int n0   = (blk & 15) * 64;
    const int row0 = b * 1024 + n0;

    const int xsl  = XH_OFF + w * 1024;
    const int fidx0 = l15 * 64 + (((0 + quad) ^ (l15 & 7)) * 8);
    const int fidx1 = l15 * 64 + (((4 + quad) ^ (l15 & 7)) * 8);
    const int rl   = lane >> 2;
    const int c8a  = 2 * (lane & 3);
    const int c8b  = 2 * (lane & 3) + 1;
    const int sidx_a = rl * 64 + ((c8a ^ (rl & 7)) * 8);
    const int sidx_b = rl * 64 + ((c8b ^ (rl & 7)) * 8);

    const int vl    = valid_len[b];
    const int nt    = (vl == 0) ? 16 : ((vl + 63) >> 6);
    const int fullt = vl >> 6;

    {
        const float* xrow = x + (size_t)(row0 + w * 16) * 64;
#pragma unroll
        for (int i = 0; i < 2; ++i) {
            int c8 = (i == 0) ? c8a : c8b;
            int sidx = (i == 0) ? sidx_a : sidx_b;
            const float4* gp = (const float4*)(xrow + rl * 64 + c8 * 8);
            float4 f0 = gp[0], f1 = gp[1];
            float fv[8] = { f0.x, f0.y, f0.z, f0.w, f1.x, f1.y, f1.z, f1.w };
            __align__(16) unsigned short thi[8], tlo[8];
#pragma unroll
            for (int j = 0; j < 8; ++j) {
                unsigned short hi = f2h(fv[j]);
                thi[j] = hi;
                tlo[j] = f2h(fv[j] - h2f(hi));
            }
            *(uint4*)&smem[xsl + sidx]                = *(uint4*)thi;
            *(uint4*)&smem[VS0_OFF + w * 1024 + sidx] = *(uint4*)tlo;
        }
    }
    {
        int g = tid & 63, ci = tid >> 6;
#pragma unroll
        for (int j = 0; j < 16; ++j) {
            int c = ci * 16 + j;
            int idx = g * 64 + (((c >> 3) ^ (g & 7)) * 8) + (c & 7);
            float fq = Wq[c * 64 + g];
            unsigned short qhi = f2h(fq);
            smem[KL0_OFF + idx] = qhi;
            smem[KL1_OFF + idx] = f2h(fq - h2f(qhi));
            smem[VS1_OFF + idx] = f2h(Wk[c * 64 + g]);
            smem[PS_OFF  + idx] = f2h(Wv[c * 64 + g]);
        }
    }
    __syncthreads();

    halfx8 wkf0[4], wkf1[4], wvf0[4], wvf1[4];
#pragma unroll
    for (int gs = 0; gs < 4; ++gs) {
        int brow = gs * 16 + l15;
        int b0 = brow * 64 + (((0 + quad) ^ (brow & 7)) * 8);
        int b1 = brow * 64 + (((4 + quad) ^ (brow & 7)) * 8);
        wkf0[gs] = *(const halfx8*)&smem[VS1_OFF + b0];
        wkf1[gs] = *(const halfx8*)&smem[VS1_OFF + b1];
        wvf0[gs] = *(const halfx8*)&smem[PS_OFF + b0];
        wvf1[gs] = *(const halfx8*)&smem[PS_OFF + b1];
    }

    {
        halfx8 ah0 = *(const halfx8*)&smem[xsl + fidx0];
        halfx8 ah1 = *(const halfx8*)&smem[xsl + fidx1];
        halfx8 al0 = *(const halfx8*)&smem[VS0_OFF + w * 1024 + fidx0];
        halfx8 al1 = *(const halfx8*)&smem[VS0_OFF + w * 1024 + fidx1];
#pragma unroll
        for (int gs = 0; gs < 4; ++gs) {
            int brow = gs * 16 + l15;
            float bb = bq[gs * 16 + l15];
            floatx4 acc = { bb, bb, bb, bb };
            int b0 = brow * 64 + (((0 + quad) ^ (brow & 7)) * 8);
            int b1 = brow * 64 + (((4 + quad) ^ (brow & 7)) * 8);
            halfx8 bh0 = *(const halfx8*)&smem[KL0_OFF + b0];
            halfx8 bh1 = *(const halfx8*)&smem[KL0_OFF + b1];
            halfx8 bl0 = *(const halfx8*)&smem[KL1_OFF + b0];
            halfx8 bl1 = *(const halfx8*)&smem[KL1_OFF + b1];
            acc = MFMA16(ah0, bh0, acc);
            acc = MFMA16(ah1, bh1, acc);
            acc = MFMA16(ah0, bl0, acc);
            acc = MFMA16(ah1, bl1, acc);
            acc = MFMA16(al0, bh0, acc);
            acc = MFMA16(al1, bh1, acc);
            int c8 = gs * 2 + (l15 >> 3);
#pragma unroll
            for (int r = 0; r < 4; ++r) {
                int row = w * 16 + quad * 4 + r;
                smem[Q_OFF + row * 64 + ((c8 ^ (row & 7)) * 8) + (l15 & 7)] = f2h(acc[r]);
            }
        }
    }
    const int arow = w * 16 + l15;
    halfx8 aq0 = *(const halfx8*)&smem[Q_OFF + arow * 64 + (((0 + quad) ^ (arow & 7)) * 8)];
    halfx8 aq1 = *(const halfx8*)&smem[Q_OFF + arow * 64 + (((4 + quad) ^ (arow & 7)) * 8)];

    {
        const float* xrow = x + (size_t)(b * 1024 + w * 16) * 64;
#pragma unroll
        for (int i = 0; i < 2; ++i) {
            int c8 = (i == 0) ? c8a : c8b;
            int sidx = (i == 0) ? sidx_a : sidx_b;
            const float4* gp = (const float4*)(xrow + rl * 64 + c8 * 8);
            float4 f0 = gp[0], f1 = gp[1];
            __align__(16) unsigned short thi[8] = {
                f2h(f0.x), f2h(f0.y), f2h(f0.z), f2h(f0.w),
                f2h(f1.x), f2h(f1.y), f2h(f1.z), f2h(f1.w) };
            *(uint4*)&smem[xsl + sidx] = *(uint4*)thi;
        }
    }
    __syncthreads();

    {
        halfx8 kxh0 = *(const halfx8*)&smem[xsl + fidx0];
        halfx8 kxh1 = *(const halfx8*)&smem[xsl + fidx1];
#pragma unroll
        for (int gs = 0; gs < 4; ++gs) {
            float bbk = bk[gs * 16 + l15];
            float bbv = bv[gs * 16 + l15];
            floatx4 kacc = { bbk, bbk, bbk, bbk };
            floatx4 vacc = { bbv, bbv, bbv, bbv };
            kacc = MFMA16(kxh0, wkf0[gs], kacc);
            kacc = MFMA16(kxh1, wkf1[gs], kacc);
            vacc = MFMA16(kxh0, wvf0[gs], vacc);
            vacc = MFMA16(kxh1, wvf1[gs], vacc);
            int c8 = gs * 2 + (l15 >> 3);
            int g  = gs * 16 + l15;
#pragma unroll
            for (int r = 0; r < 4; ++r) {
                int key = w * 16 + quad * 4 + r;
                smem[KL0_OFF + key * 64 + ((c8 ^ (key & 7)) * 8) + (l15 & 7)] = f2h(kacc[r]);
                smem[VS0_OFF + g * 64 + (((key >> 3) ^ (g & 7)) * 8) + (key & 7)] = f2h(vacc[r]);
            }
        }
    }

    float m_r[4]    = { -INFINITY, -INFINITY, -INFINITY, -INFINITY };
    float l_lane[4] = { 0.f, 0.f, 0.f, 0.f };
    floatx4 o[4] = { {0,0,0,0}, {0,0,0,0}, {0,0,0,0}, {0,0,0,0} };

    for (int t = 0; t < nt; ++t) {
        bool pre = (t + 1) < nt;
        float4 pfa0, pfa1, pfb0, pfb1;
        if (pre) {
            const float* xrow = x + (size_t)(b * 1024 + (t + 1) * 64 + w * 16) * 64;
            pfa0 = ((const float4*)(xrow + rl * 64 + c8a * 8))[0];
            pfa1 = ((const float4*)(xrow + rl * 64 + c8a * 8))[1];
            pfb0 = ((const float4*)(xrow + rl * 64 + c8b * 8))[0];
            pfb1 = ((const float4*)(xrow + rl * 64 + c8b * 8))[1];
        }
        __syncthreads();

        if (pre) {
            __align__(16) unsigned short ta[8] = {
                f2h(pfa0.x), f2h(pfa0.y), f2h(pfa0.z), f2h(pfa0.w),
                f2h(pfa1.x), f2h(pfa1.y), f2h(pfa1.z), f2h(pfa1.w) };
            __align__(16) unsigned short tb[8] = {
                f2h(pfb0.x), f2h(pfb0.y), f2h(pfb0.z), f2h(pfb0.w),
                f2h(pfb1.x), f2h(pfb1.y), f2h(pfb1.z), f2h(pfb1.w) };
            *(uint4*)&smem[xsl + sidx_a] = *(uint4*)ta;
            *(uint4*)&smem[xsl + sidx_b] = *(uint4*)tb;
            halfx8 kxh0 = *(const halfx8*)&smem[xsl + fidx0];
            halfx8 kxh1 = *(const halfx8*)&smem[xsl + fidx1];
            const int KLn = ((t + 1) & 1) ? KL1_OFF : KL0_OFF;
            const int VSn = ((t + 1) & 1) ? VS1_OFF : VS0_OFF;
#pragma unroll
            for (int gs = 0; gs < 4; ++gs) {
                float bbk = bk[gs * 16 + l15];
                float bbv = bv[gs * 16 + l15];
                floatx4 kacc = { bbk, bbk, bbk, bbk };
                floatx4 vacc = { bbv, bbv, bbv, bbv };
                kacc = MFMA16(kxh0, wkf0[gs], kacc);
                kacc = MFMA16(kxh1, wkf1[gs], kacc);
                vacc = MFMA16(kxh0, wvf0[gs], vacc);
                vacc = MFMA16(kxh1, wvf1[gs], vacc);
                int c8 = gs * 2 + (l15 >> 3);
                int g  = gs * 16 + l15;
#pragma unroll
                for (int r = 0; r < 4; ++r) {
                    int key = w * 16 + quad * 4 + r;
                    smem[KLn + key * 64 + ((c8 ^ (key & 7)) * 8) + (l15 & 7)] = f2h(kacc[r]);
                    smem[VSn + g * 64 + (((key >> 3) ^ (g & 7)) * 8) + (key & 7)] = f2h(vacc[r]);
                }
            }
        }

        const int KLc = (t & 1) ? KL1_OFF : KL0_OFF;
        const int VSc = (t & 1) ? VS1_OFF : VS0_OFF;

        floatx4 s[4];
#pragma unroll
        for (int sub = 0; sub < 4; ++sub) {
            int krow = sub * 16 + l15;
            halfx8 bk0 = *(const halfx8*)&smem[KLc + krow * 64 + (((0 + quad) ^ (krow & 7)) * 8)];
            halfx8 bk1 = *(const halfx8*)&smem[KLc + krow * 64 + (((4 + quad) ^ (krow & 7)) * 8)];
            floatx4 acc = { 0, 0, 0, 0 };
            acc = MFMA16(aq0, bk0, acc);
            acc = MFMA16(aq1, bk1, acc);
            s[sub] = acc;
        }
        if (t >= fullt) {
#pragma unroll
            for (int sub = 0; sub < 4; ++sub) {
                int key = t * 64 + sub * 16 + l15;
                if (key >= vl) { s[sub][0] = -1e6f; s[sub][1] = -1e6f; s[sub][2] = -1e6f; s[sub][3] = -1e6f; }
            }
        }

        float p[4][4];
        float alpha[4];
#pragma unroll
        for (int r = 0; r < 4; ++r) {
            float mx = fmaxf(fmaxf(s[0][r], s[1][r]), fmaxf(s[2][r], s[3][r]));
#pragma unroll
            for (int off = 1; off < 16; off <<= 1)
                mx = fmaxf(mx, __shfl_xor(mx, off, 64));
            float mnew = fmaxf(m_r[r], mx);
            alpha[r] = __expf(m_r[r] - mnew);
            float psum = 0.f;
#pragma unroll
            for (int sub = 0; sub < 4; ++sub) {
                float pv = __expf(s[sub][r] - mnew);
                p[sub][r] = pv;
                psum += pv;
            }
            l_lane[r] = l_lane[r] * alpha[r] + psum;
            m_r[r] = mnew;
        }
#pragma unroll
        for (int gs = 0; gs < 4; ++gs) {
            o[gs][0] *= alpha[0]; o[gs][1] *= alpha[1];
            o[gs][2] *= alpha[2]; o[gs][3] *= alpha[3];
        }

        unsigned short* psw = &smem[PS_OFF + w * 1024];
#pragma unroll
        for (int sub = 0; sub < 4; ++sub) {
            int c8 = sub * 2 + (l15 >> 3);
#pragma unroll
            for (int r = 0; r < 4; ++r) {
                int row = quad * 4 + r;
                psw[row * 64 + ((c8 ^ (row & 7)) * 8) + (l15 & 7)] = f2h(p[sub][r]);
            }
        }
        halfx8 ap0 = *(const halfx8*)&psw[fidx0];
        halfx8 ap1 = *(const halfx8*)&psw[fidx1];

#pragma unroll
        for (int gs = 0; gs < 4; ++gs) {
            int grow = gs * 16 + l15;
            halfx8 bv0 = *(const halfx8*)&smem[VSc + grow * 64 + (((0 + quad) ^ (grow & 7)) * 8)];
            halfx8 bv1 = *(const halfx8*)&smem[VSc + grow * 64 + (((4 + quad) ^ (grow & 7)) * 8)];
            o[gs] = MFMA16(ap0, bv0, o[gs]);
            o[gs] = MFMA16(ap1, bv1, o[gs]);
        }
    }

    float l[4];
#pragma unroll
    for (int r = 0; r < 4; ++r) {
        float ss = l_lane[r];
#pragma unroll
        for (int off = 1; off < 16; off <<= 1)
            ss += __shfl_xor(ss, off, 64);
        l[r] = ss;
    }
#pragma unroll
    for (int gs = 0; gs < 4; ++gs) {
#pragma unroll
        for (int r = 0; r < 4; ++r) {
            int row = row0 + w * 16 + quad * 4 + r;
            out[row * 64 + gs * 16 + l15] = o[gs][r] / l[r];
        }
    }
}

// ---------------------------------------------------------------------------
extern "C" void kernel_launch(void* const* d_in, const int* in_sizes, int n_in,
                              void* d_out, int out_size, void* d_ws, size_t ws_size,
                              hipStream_t stream) {
    const float* x    = (const float*)d_in[0];
    const int*   vlen = (const int*)  d_in[1];
    const float* Wq   = (const float*)d_in[2];
    const float* bq   = (const float*)d_in[3];
    const float* Wk   = (const float*)d_in[4];
    const float* bk   = (const float*)d_in[5];
    const float* Wv   = (const float*)d_in[6];
    const float* bv   = (const float*)d_in[7];
    float* out = (float*)d_out;

    const size_t IMG_SHORTS = (size_t)32 * 16 * 4096;         // 4 MB per image
    const size_t NEED = 3 * IMG_SHORTS * sizeof(unsigned short);  // 12 MB

    if (ws_size >= NEED) {
        unsigned short* qimg = (unsigned short*)d_ws;
        unsigned short* kimg = qimg + IMG_SHORTS;
        unsigned short* vimg = kimg + IMG_SHORTS;
        proj_kernel<<<512, 256, 0, stream>>>(x, Wq, bq, Wk, bk, Wv, bv, vlen,
                                             qimg, kimg, vimg);
        attn_kernel<<<512, 256, 0, stream>>>(qimg, kimg, vimg, vlen, out);
    } else {
        fused_attn_fallback<<<512, 256, 0, stream>>>(
            x, Wq, bq, Wk, bk, Wv, bv, vlen, out);
    }
}

// Round 5
// 97.049 us; speedup vs baseline: 1.0877x; 1.0877x over previous
//
#include <hip/hip_runtime.h>
#include <stdint.h>

// Problem constants: B=32, N=1024, C=64, G=64
//
// R20 = R18 base (99.1us, best) + one-tile-deferred PV pipeline.
// R19 postmortem: XCD remap + dual-prefetch regressed 6.5us (>> 1.5us noise)
// -> reverted; workgroup->XCD mapping is undefined and the remap risked
// concentrating heavy batches. R20 keeps R18's proven mapping/prefetch and
// removes the intra-tile P-staging round-trip from the critical path:
//   tile T: QK(T) -> softmax(T) -> [PV(T-1) from LDS buf written LAST tile
//   + V(T-1) regs; o = o*alpha(T-1) + P(T-1)V(T-1)] -> load V(T+1) into the
//   just-freed V reg set (~1.7-tile prefetch distance) -> stage P(T).
//   K(T+1) loads in-place into kf after QK consumes it (no copy, -32 VGPR).
// Even/odd tile bodies are macro-expanded (static reg/buffer names; no
// runtime-indexed ext_vector arrays). Identical op sequence per output
// element -> bit-identical results (absmax 0.015625).
// Fallback: if ws_size < 12MB, launch the unmodified R15 kernel.

typedef __attribute__((ext_vector_type(4))) float    floatx4;
typedef __attribute__((ext_vector_type(8))) _Float16 halfx8;

static __device__ __forceinline__ unsigned short f2h(float f) {
    union { _Float16 h; unsigned short u; } v; v.h = (_Float16)f;
    return v.u;
}
static __device__ __forceinline__ float h2f(unsigned short u) {
    union { unsigned short u; _Float16 h; } v; v.u = u;
    return (float)v.h;
}

#define MFMA16(a, bb, c) __builtin_amdgcn_mfma_f32_16x16x32_f16((a), (bb), (c), 0, 0, 0)

// ============================================================================
// Pass 1: projections (verbatim R18). Block blk = b*16 + tile handles x rows
// blk*64..blk*64+63; writes three 8KB pre-swizzled fp16 images per block:
//   Q/K image: img[row*64 + ((c8 ^ (row&7))*8) + j] = P[row][c8*8+j]
//   V image  : img[g*64  + ((kc8 ^ (g&7))*8) + j]   = V[kc8*8+j][g]   (V^T)
// ============================================================================
__global__ __launch_bounds__(256, 2) void proj_kernel(
    const float* __restrict__ x,
    const float* __restrict__ Wq, const float* __restrict__ bq,
    const float* __restrict__ Wk, const float* __restrict__ bk,
    const float* __restrict__ Wv, const float* __restrict__ bv,
    unsigned short* __restrict__ qimg,
    unsigned short* __restrict__ kimg,
    unsigned short* __restrict__ vimg)
{
    __shared__ __align__(16) unsigned short sm[24576];   // 48 KB
    const int XH = 0, XL = 4096, WQH = 8192, WQL = 12288, WKH = 16384, WVH = 20480;

    const int tid  = threadIdx.x;
    const int blk  = blockIdx.x;          // 0..511
    const int lane = tid & 63;
    const int w    = tid >> 6;
    const int l15  = lane & 15;
    const int quad = lane >> 4;
    const int rl   = lane >> 2;
    const int c8a  = 2 * (lane & 3);
    const int c8b  = c8a + 1;
    const int sidx_a = rl * 64 + ((c8a ^ (rl & 7)) * 8);
    const int sidx_b = rl * 64 + ((c8b ^ (rl & 7)) * 8);

    // ---- stage x (hi + lo residual), wave-private 16-row slices ----
    {
        const float* xrow = x + (size_t)(blk * 64 + w * 16) * 64;
#pragma unroll
        for (int i = 0; i < 2; ++i) {
            int c8   = (i == 0) ? c8a : c8b;
            int sidx = (i == 0) ? sidx_a : sidx_b;
            const float4* gp = (const float4*)(xrow + rl * 64 + c8 * 8);
            float4 f0 = gp[0], f1 = gp[1];
            float fv[8] = { f0.x, f0.y, f0.z, f0.w, f1.x, f1.y, f1.z, f1.w };
            __align__(16) unsigned short thi[8], tlo[8];
#pragma unroll
            for (int j = 0; j < 8; ++j) {
                unsigned short hi = f2h(fv[j]);
                thi[j] = hi;
                tlo[j] = f2h(fv[j] - h2f(hi));
            }
            *(uint4*)&sm[XH + w * 1024 + sidx] = *(uint4*)thi;
            *(uint4*)&sm[XL + w * 1024 + sidx] = *(uint4*)tlo;
        }
    }
    // ---- stage Wq(hi,lo), Wk, Wv  ([g][c] transposed, XOR-swizzled) ----
    {
        int g = tid & 63, ci = tid >> 6;
#pragma unroll
        for (int j = 0; j < 16; ++j) {
            int c = ci * 16 + j;
            int idx = g * 64 + (((c >> 3) ^ (g & 7)) * 8) + (c & 7);
            float fq = Wq[c * 64 + g];
            unsigned short qhi = f2h(fq);
            sm[WQH + idx] = qhi;
            sm[WQL + idx] = f2h(fq - h2f(qhi));
            sm[WKH + idx] = f2h(Wk[c * 64 + g]);
            sm[WVH + idx] = f2h(Wv[c * 64 + g]);
        }
    }
    __syncthreads();

    const int fidx0 = l15 * 64 + (((0 + quad) ^ (l15 & 7)) * 8);
    const int fidx1 = l15 * 64 + (((4 + quad) ^ (l15 & 7)) * 8);
    halfx8 ah0 = *(const halfx8*)&sm[XH + w * 1024 + fidx0];
    halfx8 ah1 = *(const halfx8*)&sm[XH + w * 1024 + fidx1];
    halfx8 al0 = *(const halfx8*)&sm[XL + w * 1024 + fidx0];
    halfx8 al1 = *(const halfx8*)&sm[XL + w * 1024 + fidx1];

    floatx4 vacc[4];
#pragma unroll
    for (int gs = 0; gs < 4; ++gs) {
        int brow = gs * 16 + l15;
        int b0 = brow * 64 + (((0 + quad) ^ (brow & 7)) * 8);
        int b1 = brow * 64 + (((4 + quad) ^ (brow & 7)) * 8);
        halfx8 bh0 = *(const halfx8*)&sm[WQH + b0];
        halfx8 bh1 = *(const halfx8*)&sm[WQH + b1];
        halfx8 bl0 = *(const halfx8*)&sm[WQL + b0];
        halfx8 bl1 = *(const halfx8*)&sm[WQL + b1];
        halfx8 wk0 = *(const halfx8*)&sm[WKH + b0];
        halfx8 wk1 = *(const halfx8*)&sm[WKH + b1];
        halfx8 wv0 = *(const halfx8*)&sm[WVH + b0];
        halfx8 wv1 = *(const halfx8*)&sm[WVH + b1];

        float bbq = bq[gs * 16 + l15];
        floatx4 qa = { bbq, bbq, bbq, bbq };
        qa = MFMA16(ah0, bh0, qa);
        qa = MFMA16(ah1, bh1, qa);
        qa = MFMA16(ah0, bl0, qa);
        qa = MFMA16(ah1, bl1, qa);
        qa = MFMA16(al0, bh0, qa);
        qa = MFMA16(al1, bh1, qa);

        float bbk = bk[gs * 16 + l15];
        float bbv = bv[gs * 16 + l15];
        floatx4 ka = { bbk, bbk, bbk, bbk };
        floatx4 va = { bbv, bbv, bbv, bbv };
        ka = MFMA16(ah0, wk0, ka);
        ka = MFMA16(ah1, wk1, ka);
        va = MFMA16(ah0, wv0, va);
        va = MFMA16(ah1, wv1, va);
        vacc[gs] = va;

        int c8 = gs * 2 + (l15 >> 3);
#pragma unroll
        for (int r = 0; r < 4; ++r) {
            int row = w * 16 + quad * 4 + r;
            int idx = row * 64 + ((c8 ^ (row & 7)) * 8) + (l15 & 7);
            sm[XH + idx] = f2h(qa[r]);
            sm[XL + idx] = f2h(ka[r]);
        }
    }
    __syncthreads();   // all waves done reading Wq-hi -> WQH reusable as V image
#pragma unroll
    for (int gs = 0; gs < 4; ++gs) {
        int g = gs * 16 + l15;
#pragma unroll
        for (int r = 0; r < 4; ++r) {
            int key = w * 16 + quad * 4 + r;
            sm[WQH + g * 64 + (((key >> 3) ^ (g & 7)) * 8) + (key & 7)] = f2h(vacc[gs][r]);
        }
    }
    __syncthreads();

    // ---- cooperative copy: 3 x 8KB images -> global workspace ----
    {
        const size_t tb = (size_t)blk * 4096;   // shorts per image
#pragma unroll
        for (int i = 0; i < 2; ++i) {
            int ci = i * 256 + tid;             // 512 x 16B chunks per image
            *(uint4*)&qimg[tb + ci * 8] = *(const uint4*)&sm[XH  + ci * 8];
            *(uint4*)&kimg[tb + ci * 8] = *(const uint4*)&sm[XL  + ci * 8];
            *(uint4*)&vimg[tb + ci * 8] = *(const uint4*)&sm[WQH + ci * 8];
        }
    }
}

// ============================================================================
// Pass 2: barrier-free attention with one-tile-deferred PV.
// V(t) lives in reg set [t&1] (vfA=even, vfB=odd); P(t) in LDS buf[t&1].
// Tile T: QK(T); K(T+1)->kf in place; softmax(T); o = o*alpha(T-1) +
// P(T-1)V(T-1) [LDS buf (T-1)&1, V set (T-1)&1]; V(T+1) -> same set; stage
// P(T). Epilogue drains PV(nt-1).
// ============================================================================
__global__ __launch_bounds__(256, 2) void attn_kernel(
    const unsigned short* __restrict__ qimg,
    const unsigned short* __restrict__ kimg,
    const unsigned short* __restrict__ vimg,
    const int* __restrict__ valid_len, float* __restrict__ out)
{
    __shared__ __align__(16) unsigned short psmem[8192];  // 16 KB: 2 bufs x 4 waves x 2KB
    __shared__ int sched[32];

    const int tid  = threadIdx.x;
    const int blk  = blockIdx.x;          // 0..511
    const int lane = tid & 63;
    const int w    = tid >> 6;
    const int l15  = lane & 15;
    const int quad = lane >> 4;

    // ---------- device-side balanced schedule (identical in every block) ----
    if (tid < 32) {
        int vlb = valid_len[tid];
        int ntb = (vlb == 0) ? 16 : ((vlb + 63) >> 6);
        int rank = 0;
        for (int b2 = 0; b2 < 32; ++b2) {
            int vl2 = valid_len[b2];
            int nt2 = (vl2 == 0) ? 16 : ((vl2 + 63) >> 6);
            rank += (nt2 > ntb) || (nt2 == ntb && b2 < tid);
        }
        sched[rank] = tid;
    }
    __syncthreads();   // the ONLY block-wide barrier

    const int b    = (blk < 256) ? sched[blk >> 4] : sched[31 - ((blk - 256) >> 4)];
    const int qt   = blk & 15;
    const int row0 = b * 1024 + qt * 64;

    const int vl    = valid_len[b];
    const int nt    = (vl == 0) ? 16 : ((vl + 63) >> 6);
    const int fullt = vl >> 6;

    // ---- Q fragments straight from the global image ----
    const int arow = w * 16 + l15;
    const unsigned short* qb = qimg + (size_t)(b * 16 + qt) * 4096;
    halfx8 aq0 = *(const halfx8*)&qb[arow * 64 + (((0 + quad) ^ (arow & 7)) * 8)];
    halfx8 aq1 = *(const halfx8*)&qb[arow * 64 + (((4 + quad) ^ (arow & 7)) * 8)];

    // ---- fragment indices within a 4096-short tile image ----
    int idx0[4], idx1[4];
#pragma unroll
    for (int sub = 0; sub < 4; ++sub) {
        int r = sub * 16 + l15;
        idx0[sub] = r * 64 + (((0 + quad) ^ (r & 7)) * 8);
        idx1[sub] = r * 64 + (((4 + quad) ^ (r & 7)) * 8);
    }
    const int fpidx0 = l15 * 64 + (((0 + quad) ^ (l15 & 7)) * 8);
    const int fpidx1 = l15 * 64 + (((4 + quad) ^ (l15 & 7)) * 8);

    const unsigned short* kt_base = kimg + (size_t)b * 65536;
    const unsigned short* vt_base = vimg + (size_t)b * 65536;

    float m_r[4]    = { -INFINITY, -INFINITY, -INFINITY, -INFINITY };
    float l_lane[4] = { 0.f, 0.f, 0.f, 0.f };
    float aprev[4]  = { 0.f, 0.f, 0.f, 0.f };
    floatx4 o[4] = { {0,0,0,0}, {0,0,0,0}, {0,0,0,0}, {0,0,0,0} };

    unsigned short* psw0 = &psmem[w * 1024];          // P buf parity 0
    unsigned short* psw1 = &psmem[4096 + w * 1024];   // P buf parity 1

    // preload K(0) -> kf, V(0) -> vfA (parity-0 set)
    halfx8 kf0[4], kf1[4];
    halfx8 vfA0[4], vfA1[4], vfB0[4], vfB1[4];
#pragma unroll
    for (int sub = 0; sub < 4; ++sub) {
        kf0[sub]  = *(const halfx8*)&kt_base[idx0[sub]];
        kf1[sub]  = *(const halfx8*)&kt_base[idx1[sub]];
        vfA0[sub] = *(const halfx8*)&vt_base[idx0[sub]];
        vfA1[sub] = *(const halfx8*)&vt_base[idx1[sub]];
    }

    // ---- one tile of work; PV is one tile DEFERRED (verbatim arithmetic) ----
#define TILE_BODY(T, VS0, VS1, PW, PR)                                         \
    {                                                                          \
        floatx4 s_[4];                                                         \
        _Pragma("unroll")                                                      \
        for (int sub = 0; sub < 4; ++sub) {                                    \
            floatx4 acc = { 0, 0, 0, 0 };                                      \
            acc = MFMA16(aq0, kf0[sub], acc);                                  \
            acc = MFMA16(aq1, kf1[sub], acc);                                  \
            s_[sub] = acc;                                                     \
        }                                                                      \
        if ((T) + 1 < nt) {      /* K(T) consumed -> load K(T+1) in place */   \
            const unsigned short* ktn = kt_base + (size_t)((T) + 1) * 4096;    \
            _Pragma("unroll")                                                  \
            for (int sub = 0; sub < 4; ++sub) {                                \
                kf0[sub] = *(const halfx8*)&ktn[idx0[sub]];                    \
                kf1[sub] = *(const halfx8*)&ktn[idx1[sub]];                    \
            }                                                                  \
        }                                                                      \
        if ((T) >= fullt) {                                                    \
            _Pragma("unroll")                                                  \
            for (int sub = 0; sub < 4; ++sub) {                                \
                int key = (T) * 64 + sub * 16 + l15;                           \
                if (key >= vl) { s_[sub][0] = -1e6f; s_[sub][1] = -1e6f;       \
                                 s_[sub][2] = -1e6f; s_[sub][3] = -1e6f; }     \
            }                                                                  \
        }                                                                      \
        float p_[4][4];                                                        \
        float alpha_[4];                                                       \
        _Pragma("unroll")                                                      \
        for (int r = 0; r < 4; ++r) {                                          \
            float mx = fmaxf(fmaxf(s_[0][r], s_[1][r]),                        \
                             fmaxf(s_[2][r], s_[3][r]));                       \
            _Pragma("unroll")                                                  \
            for (int off = 1; off < 16; off <<= 1)                             \
                mx = fmaxf(mx, __shfl_xor(mx, off, 64));                       \
            float mnew = fmaxf(m_r[r], mx);                                    \
            alpha_[r] = __expf(m_r[r] - mnew);                                 \
            float psum = 0.f;                                                  \
            _Pragma("unroll")                                                  \
            for (int sub = 0; sub < 4; ++sub) {                                \
                float pv = __expf(s_[sub][r] - mnew);                          \
                p_[sub][r] = pv;                                               \
                psum += pv;                                                    \
            }                                                                  \
            l_lane[r] = l_lane[r] * alpha_[r] + psum;                          \
            m_r[r] = mnew;                                                     \
        }                                                                      \
        {   /* deferred PV(T-1): o = o*alpha(T-1) + P(T-1)V(T-1) */            \
            halfx8 ap0 = *(const halfx8*)&(PR)[fpidx0];                        \
            halfx8 ap1 = *(const halfx8*)&(PR)[fpidx1];                        \
            _Pragma("unroll")                                                  \
            for (int gs = 0; gs < 4; ++gs) {                                   \
                o[gs][0] *= aprev[0]; o[gs][1] *= aprev[1];                    \
                o[gs][2] *= aprev[2]; o[gs][3] *= aprev[3];                    \
                o[gs] = MFMA16(ap0, VS0[gs], o[gs]);                           \
                o[gs] = MFMA16(ap1, VS1[gs], o[gs]);                           \
            }                                                                  \
        }                                                                      \
        if ((T) + 1 < nt) {      /* V(T-1) consumed -> load V(T+1) there */    \
            const unsigned short* vtn = vt_base + (size_t)((T) + 1) * 4096;    \
            _Pragma("unroll")                                                  \
            for (int sub = 0; sub < 4; ++sub) {                                \
                VS0[sub] = *(const halfx8*)&vtn[idx0[sub]];                    \
                VS1[sub] = *(const halfx8*)&vtn[idx1[sub]];                    \
            }                                                                  \
        }                                                                      \
        _Pragma("unroll")        /* stage P(T) */                              \
        for (int sub = 0; sub < 4; ++sub) {                                    \
            int c8 = sub * 2 + (l15 >> 3);                                     \
            _Pragma("unroll")                                                  \
            for (int r = 0; r < 4; ++r) {                                      \
                int row = quad * 4 + r;                                        \
                (PW)[row * 64 + ((c8 ^ (row & 7)) * 8) + (l15 & 7)] =          \
                    f2h(p_[sub][r]);                                           \
            }                                                                  \
        }                                                                      \
        aprev[0] = alpha_[0]; aprev[1] = alpha_[1];                            \
        aprev[2] = alpha_[2]; aprev[3] = alpha_[3];                            \
    }

    // ---- peeled tile 0: no PV yet; V(1) -> vfB; P(0) -> psw0 ----
    {
        floatx4 s_[4];
#pragma unroll
        for (int sub = 0; sub < 4; ++sub) {
            floatx4 acc = { 0, 0, 0, 0 };
            acc = MFMA16(aq0, kf0[sub], acc);
            acc = MFMA16(aq1, kf1[sub], acc);
            s_[sub] = acc;
        }
        if (nt > 1) {
            const unsigned short* ktn = kt_base + 4096;
#pragma unroll
            for (int sub = 0; sub < 4; ++sub) {
                kf0[sub] = *(const halfx8*)&ktn[idx0[sub]];
                kf1[sub] = *(const halfx8*)&ktn[idx1[sub]];
            }
        }
        if (0 >= fullt) {
#pragma unroll
            for (int sub = 0; sub < 4; ++sub) {
                int key = sub * 16 + l15;
                if (key >= vl) { s_[sub][0] = -1e6f; s_[sub][1] = -1e6f;
                                 s_[sub][2] = -1e6f; s_[sub][3] = -1e6f; }
            }
        }
        float p_[4][4];
        float alpha_[4];
#pragma unroll
        for (int r = 0; r < 4; ++r) {
            float mx = fmaxf(fmaxf(s_[0][r], s_[1][r]), fmaxf(s_[2][r], s_[3][r]));
#pragma unroll
            for (int off = 1; off < 16; off <<= 1)
                mx = fmaxf(mx, __shfl_xor(mx, off, 64));
            float mnew = fmaxf(m_r[r], mx);
            alpha_[r] = __expf(m_r[r] - mnew);
            float psum = 0.f;
#pragma unroll
            for (int sub = 0; sub < 4; ++sub) {
                float pv = __expf(s_[sub][r] - mnew);
                p_[sub][r] = pv;
                psum += pv;
            }
            l_lane[r] = l_lane[r] * alpha_[r] + psum;
            m_r[r] = mnew;
        }
        if (nt > 1) {
            const unsigned short* vtn = vt_base + 4096;
#pragma unroll
            for (int sub = 0; sub < 4; ++sub) {
                vfB0[sub] = *(const halfx8*)&vtn[idx0[sub]];
                vfB1[sub] = *(const halfx8*)&vtn[idx1[sub]];
            }
        }
#pragma unroll
        for (int sub = 0; sub < 4; ++sub) {
            int c8 = sub * 2 + (l15 >> 3);
#pragma unroll
            for (int r = 0; r < 4; ++r) {
                int row = quad * 4 + r;
                psw0[row * 64 + ((c8 ^ (row & 7)) * 8) + (l15 & 7)] = f2h(p_[sub][r]);
            }
        }
        aprev[0] = alpha_[0]; aprev[1] = alpha_[1];
        aprev[2] = alpha_[2]; aprev[3] = alpha_[3];
    }

    // ---- main loop: odd/even bodies with static parity ----
    int t = 1;
    for (; t + 1 < nt; t += 2) {
        TILE_BODY(t,     vfA0, vfA1, psw1, psw0);   // odd T: consume V(even)=vfA
        TILE_BODY(t + 1, vfB0, vfB1, psw0, psw1);   // even T: consume V(odd)=vfB
    }
    if (t < nt) {
        TILE_BODY(t, vfA0, vfA1, psw1, psw0);       // trailing odd tile
    }
#undef TILE_BODY

    // ---- epilogue: drain PV(nt-1) ----
    if (((nt - 1) & 1) == 0) {
        halfx8 ap0 = *(const halfx8*)&psw0[fpidx0];
        halfx8 ap1 = *(const halfx8*)&psw0[fpidx1];
#pragma unroll
        for (int gs = 0; gs < 4; ++gs) {
            o[gs][0] *= aprev[0]; o[gs][1] *= aprev[1];
            o[gs][2] *= aprev[2]; o[gs][3] *= aprev[3];
            o[gs] = MFMA16(ap0, vfA0[gs], o[gs]);
            o[gs] = MFMA16(ap1, vfA1[gs], o[gs]);
        }
    } else {
        halfx8 ap0 = *(const halfx8*)&psw1[fpidx0];
        halfx8 ap1 = *(const halfx8*)&psw1[fpidx1];
#pragma unroll
        for (int gs = 0; gs < 4; ++gs) {
            o[gs][0] *= aprev[0]; o[gs][1] *= aprev[1];
            o[gs][2] *= aprev[2]; o[gs][3] *= aprev[3];
            o[gs] = MFMA16(ap0, vfB0[gs], o[gs]);
            o[gs] = MFMA16(ap1, vfB1[gs], o[gs]);
        }
    }

    // ---- final 16-lane sum butterfly, store ----
    float l[4];
#pragma unroll
    for (int r = 0; r < 4; ++r) {
        float ss = l_lane[r];
#pragma unroll
        for (int off = 1; off < 16; off <<= 1)
            ss += __shfl_xor(ss, off, 64);
        l[r] = ss;
    }
#pragma unroll
    for (int gs = 0; gs < 4; ++gs) {
#pragma unroll
        for (int r = 0; r < 4; ++r) {
            int row = row0 + w * 16 + quad * 4 + r;
            out[row * 64 + gs * 16 + l15] = o[gs][r] / l[r];
        }
    }
}

// ============================================================================
// Fallback: unmodified R15 single-pass kernel (used if ws_size < 12 MB)
// ============================================================================
__global__ __launch_bounds__(256, 2) void fused_attn_fallback(
    const float* __restrict__ x,
    const float* __restrict__ Wq, const float* __restrict__ bq,
    const float* __restrict__ Wk, const float* __restrict__ bk,
    const float* __restrict__ Wv, const float* __restrict__ bv,
    const int* __restrict__ valid_len, float* __restrict__ out)
{
    __shared__ __align__(16) unsigned short smem[28672];   // 56 KB
    __shared__ int sched[32];

    const int Q_OFF = 0, XH_OFF = 4096, KL0_OFF = 8192, KL1_OFF = 12288,
              VS0_OFF = 16384, VS1_OFF = 20480, PS_OFF = 24576;

    const int tid  = threadIdx.x;
    const int blk  = blockIdx.x;
    const int lane = tid & 63;
    const int w    = tid >> 6;
    const int l15  = lane & 15;
    const int quad = lane >> 4;

    if (tid < 32) {
        int vlb = valid_len[tid];
        int ntb = (vlb == 0) ? 16 : ((vlb + 63) >> 6);
        int rank = 0;
        for (int b2 = 0; b2 < 32; ++b2) {
            int vl2 = valid_len[b2];
            int nt2 = (vl2 == 0) ? 16 : ((vl2 + 63) >> 6);
            rank += (nt2 > ntb) || (nt2 == ntb && b2 < tid);
        }
        sched[rank] = tid;
    }
    __syncthreads();

    const int hv   = (blk < 256);
    const int b    = hv ? sched[blk >> 4] : sched[31 - ((blk - 256) >> 4)];
    const int n0   = (blk & 15) * 64;
    const int row0 = b * 1024 + n0;

    const int xsl  = XH_OFF + w * 1024;
    const int fidx0 = l15 * 64 + (((0 + quad) ^ (l15 & 7)) * 8);
    const int fidx1 = l15 * 64 + (((4 + quad) ^ (l15 & 7)) * 8);
    const int rl   = lane >> 2;
    const int c8a  = 2 * (lane & 3);
    const int c8b  = 2 * (lane & 3) + 1;
    const int sidx_a = rl * 64 + ((c8a ^ (rl & 7)) * 8);
    const int sidx_b = rl * 64 + ((c8b ^ (rl & 7)) * 8);

    const int vl    = valid_len[b];
    const int nt    = (vl == 0) ? 16 : ((vl + 63) >> 6);
    const int fullt = vl >> 6;

    {
        const float* xrow = x + (size_t)(row0 + w * 16) * 64;
#pragma unroll
        for (int i = 0; i < 2; ++i) {
            int c8 = (i == 0) ? c8a : c8b;
            int sidx = (i == 0) ? sidx_a : sidx_b;
            const float4* gp = (const float4*)(xrow + rl * 64 + c8 * 8);
            float4 f0 = gp[0], f1 = gp[1];
            float fv[8] = { f0.x, f0.y, f0.z, f0.w, f1.x, f1.y, f1.z, f1.w };
            __align__(16) unsigned short thi[8], tlo[8];
#pragma unroll
            for (int j = 0; j < 8; ++j) {
                unsigned short hi = f2h(fv[j]);
                thi[j] = hi;
                tlo[j] = f2h(fv[j] - h2f(hi));
            }
            *(uint4*)&smem[xsl + sidx]                = *(uint4*)thi;
            *(uint4*)&smem[VS0_OFF + w * 1024 + sidx] = *(uint4*)tlo;
        }
    }
    {
        int g = tid & 63, ci = tid >> 6;
#pragma unroll
        for (int j = 0; j < 16; ++j) {
            int c = ci * 16 + j;
            int idx = g * 64 + (((c >> 3) ^ (g & 7)) * 8) + (c & 7);
            float fq = Wq[c * 64 + g];
            unsigned short qhi = f2h(fq);
            smem[KL0_OFF + idx] = qhi;
            smem[KL1_OFF + idx] = f2h(fq - h2f(qhi));
            smem[VS1_OFF + idx] = f2h(Wk[c * 64 + g]);
            smem[PS_OFF  + idx] = f2h(Wv[c * 64 + g]);
        }
    }
    __syncthreads();

    halfx8 wkf0[4], wkf1[4], wvf0[4], wvf1[4];
#pragma unroll
    for (int gs = 0; gs < 4; ++gs) {
        int brow = gs * 16 + l15;
        int b0 = brow * 64 + (((0 + quad) ^ (brow & 7)) * 8);
        int b1 = brow * 64 + (((4 + quad) ^ (brow & 7)) * 8);
        wkf0[gs] = *(const halfx8*)&smem[VS1_OFF + b0];
        wkf1[gs] = *(const halfx8*)&smem[VS1_OFF + b1];
        wvf0[gs] = *(const halfx8*)&smem[PS_OFF + b0];
        wvf1[gs] = *(const halfx8*)&smem[PS_OFF + b1];
    }

    {
        halfx8 ah0 = *(const halfx8*)&smem[xsl + fidx0];
        halfx8 ah1 = *(const halfx8*)&smem[xsl + fidx1];
        halfx8 al0 = *(const halfx8*)&smem[VS0_OFF + w * 1024 + fidx0];
        halfx8 al1 = *(const halfx8*)&smem[VS0_OFF + w * 1024 + fidx1];
#pragma unroll
        for (int gs = 0; gs < 4; ++gs) {
            int brow = gs * 16 + l15;
            float bb = bq[gs * 16 + l15];
            floatx4 acc = { bb, bb, bb, bb };
            int b0 = brow * 64 + (((0 + quad) ^ (brow & 7)) * 8);
            int b1 = brow * 64 + (((4 + quad) ^ (brow & 7)) * 8);
            halfx8 bh0 = *(const halfx8*)&smem[KL0_OFF + b0];
            halfx8 bh1 = *(const halfx8*)&smem[KL0_OFF + b1];
            halfx8 bl0 = *(const halfx8*)&smem[KL1_OFF + b0];
            halfx8 bl1 = *(const halfx8*)&smem[KL1_OFF + b1];
            acc = MFMA16(ah0, bh0, acc);
            acc = MFMA16(ah1, bh1, acc);
            acc = MFMA16(ah0, bl0, acc);
            acc = MFMA16(ah1, bl1, acc);
            acc = MFMA16(al0, bh0, acc);
            acc = MFMA16(al1, bh1, acc);
            int c8 = gs * 2 + (l15 >> 3);
#pragma unroll
            for (int r = 0; r < 4; ++r) {
                int row = w * 16 + quad * 4 + r;
                smem[Q_OFF + row * 64 + ((c8 ^ (row & 7)) * 8) + (l15 & 7)] = f2h(acc[r]);
            }
        }
    }
    const int arow = w * 16 + l15;
    halfx8 aq0 = *(const halfx8*)&smem[Q_OFF + arow * 64 + (((0 + quad) ^ (arow & 7)) * 8)];
    halfx8 aq1 = *(const halfx8*)&smem[Q_OFF + arow * 64 + (((4 + quad) ^ (arow & 7)) * 8)];

    {
        const float* xrow = x + (size_t)(b * 1024 + w * 16) * 64;
#pragma unroll
        for (int i = 0; i < 2; ++i) {
            int c8 = (i == 0) ? c8a : c8b;
            int sidx = (i == 0) ? sidx_a : sidx_b;
            const float4* gp = (const float4*)(xrow + rl * 64 + c8 * 8);
            float4 f0 = gp[0], f1 = gp[1];
            __align__(16) unsigned short thi[8] = {
                f2h(f0.x), f2h(f0.y), f2h(f0.z), f2h(f0.w),
                f2h(f1.x), f2h(f1.y), f2h(f1.z), f2h(f1.w) };
            *(uint4*)&smem[xsl + sidx] = *(uint4*)thi;
        }
    }
    __syncthreads();

    {
        halfx8 kxh0 = *(const halfx8*)&smem[xsl + fidx0];
        halfx8 kxh1 = *(const halfx8*)&smem[xsl + fidx1];
#pragma unroll
        for (int gs = 0; gs < 4; ++gs) {
            float bbk = bk[gs * 16 + l15];
            float bbv = bv[gs * 16 + l15];
            floatx4 kacc = { bbk, bbk, bbk, bbk };
            floatx4 vacc = { bbv, bbv, bbv, bbv };
            kacc = MFMA16(kxh0, wkf0[gs], kacc);
            kacc = MFMA16(kxh1, wkf1[gs], kacc);
            vacc = MFMA16(kxh0, wvf0[gs], vacc);
            vacc = MFMA16(kxh1, wvf1[gs], vacc);
            int c8 = gs * 2 + (l15 >> 3);
            int g  = gs * 16 + l15;
#pragma unroll
            for (int r = 0; r < 4; ++r) {
                int key = w * 16 + quad * 4 + r;
                smem[KL0_OFF + key * 64 + ((c8 ^ (key & 7)) * 8) + (l15 & 7)] = f2h(kacc[r]);
                smem[VS0_OFF + g * 64 + (((key >> 3) ^ (g & 7)) * 8) + (key & 7)] = f2h(vacc[r]);
            }
        }
    }

    float m_r[4]    = { -INFINITY, -INFINITY, -INFINITY, -INFINITY };
    float l_lane[4] = { 0.f, 0.f, 0.f, 0.f };
    floatx4 o[4] = { {0,0,0,0}, {0,0,0,0}, {0,0,0,0}, {0,0,0,0} };

    for (int t = 0; t < nt; ++t) {
        bool pre = (t + 1) < nt;
        float4 pfa0, pfa1, pfb0, pfb1;
        if (pre) {
            const float* xrow = x + (size_t)(b * 1024 + (t + 1) * 64 + w * 16) * 64;
            pfa0 = ((const float4*)(xrow + rl * 64 + c8a * 8))[0];
            pfa1 = ((const float4*)(xrow + rl * 64 + c8a * 8))[1];
            pfb0 = ((const float4*)(xrow + rl * 64 + c8b * 8))[0];
            pfb1 = ((const float4*)(xrow + rl * 64 + c8b * 8))[1];
        }
        __syncthreads();

        if (pre) {
            __align__(16) unsigned short ta[8] = {
                f2h(pfa0.x), f2h(pfa0.y), f2h(pfa0.z), f2h(pfa0.w),
                f2h(pfa1.x), f2h(pfa1.y), f2h(pfa1.z), f2h(pfa1.w) };
            __align__(16) unsigned short tb[8] = {
                f2h(pfb0.x), f2h(pfb0.y), f2h(pfb0.z), f2h(pfb0.w),
                f2h(pfb1.x), f2h(pfb1.y), f2h(pfb1.z), f2h(pfb1.w) };
            *(uint4*)&smem[xsl + sidx_a] = *(uint4*)ta;
            *(uint4*)&smem[xsl + sidx_b] = *(uint4*)tb;
            halfx8 kxh0 = *(const halfx8*)&smem[xsl + fidx0];
            halfx8 kxh1 = *(const halfx8*)&smem[xsl + fidx1];
            const int KLn = ((t + 1) & 1) ? KL1_OFF : KL0_OFF;
            const int VSn = ((t + 1) & 1) ? VS1_OFF : VS0_OFF;
#pragma unroll
            for (int gs = 0; gs < 4; ++gs) {
                float bbk = bk[gs * 16 + l15];
                float bbv = bv[gs * 16 + l15];
                floatx4 kacc = { bbk, bbk, bbk, bbk };
                floatx4 vacc = { bbv, bbv, bbv, bbv };
                kacc = MFMA16(kxh0, wkf0[gs], kacc);
                kacc = MFMA16(kxh1, wkf1[gs], kacc);
                vacc = MFMA16(kxh0, wvf0[gs], vacc);
                vacc = MFMA16(kxh1, wvf1[gs], vacc);
                int c8 = gs * 2 + (l15 >> 3);
                int g  = gs * 16 + l15;
#pragma unroll
                for (int r = 0; r < 4; ++r) {
                    int key = w * 16 + quad * 4 + r;
                    smem[KLn + key * 64 + ((c8 ^ (key & 7)) * 8) + (l15 & 7)] = f2h(kacc[r]);
                    smem[VSn + g * 64 + (((key >> 3) ^ (g & 7)) * 8) + (key & 7)] = f2h(vacc[r]);
                }
            }
        }

        const int KLc = (t & 1) ? KL1_OFF : KL0_OFF;
        const int VSc = (t & 1) ? VS1_OFF : VS0_OFF;

        floatx4 s[4];
#pragma unroll
        for (int sub = 0; sub < 4; ++sub) {
            int krow = sub * 16 + l15;
            halfx8 bk0 = *(const halfx8*)&smem[KLc + krow * 64 + (((0 + quad) ^ (krow & 7)) * 8)];
            halfx8 bk1 = *(const halfx8*)&smem[KLc + krow * 64 + (((4 + quad) ^ (krow & 7)) * 8)];
            floatx4 acc = { 0, 0, 0, 0 };
            acc = MFMA16(aq0, bk0, acc);
            acc = MFMA16(aq1, bk1, acc);
            s[sub] = acc;
        }
        if (t >= fullt) {
#pragma unroll
            for (int sub = 0; sub < 4; ++sub) {
                int key = t * 64 + sub * 16 + l15;
                if (key >= vl) { s[sub][0] = -1e6f; s[sub][1] = -1e6f; s[sub][2] = -1e6f; s[sub][3] = -1e6f; }
            }
        }

        float p[4][4];
        float alpha[4];
#pragma unroll
        for (int r = 0; r < 4; ++r) {
            float mx = fmaxf(fmaxf(s[0][r], s[1][r]), fmaxf(s[2][r], s[3][r]));
#pragma unroll
            for (int off = 1; off < 16; off <<= 1)
                mx = fmaxf(mx, __shfl_xor(mx, off, 64));
            float mnew = fmaxf(m_r[r], mx);
            alpha[r] = __expf(m_r[r] - mnew);
            float psum = 0.f;
#pragma unroll
            for (int sub = 0; sub < 4; ++sub) {
                float pv = __expf(s[sub][r] - mnew);
                p[sub][r] = pv;
                psum += pv;
            }
            l_lane[r] = l_lane[r] * alpha[r] + psum;
            m_r[r] = mnew;
        }
#pragma unroll
        for (int gs = 0; gs < 4; ++gs) {
            o[gs][0] *= alpha[0]; o[gs][1] *= alpha[1];
            o[gs][2] *= alpha[2]; o[gs][3] *= alpha[3];
        }

        unsigned short* psw = &smem[PS_OFF + w * 1024];
#pragma unroll
        for (int sub = 0; sub < 4; ++sub) {
            int c8 = sub * 2 + (l15 >> 3);
#pragma unroll
            for (int r = 0; r < 4; ++r) {
                int row = quad * 4 + r;
                psw[row * 64 + ((c8 ^ (row & 7)) * 8) + (l15 & 7)] = f2h(p[sub][r]);
            }
        }
        halfx8 ap0 = *(const halfx8*)&psw[fidx0];
        halfx8 ap1 = *(const halfx8*)&psw[fidx1];

#pragma unroll
        for (int gs = 0; gs < 4; ++gs) {
            int grow = gs * 16 + l15;
            halfx8 bv0 = *(const halfx8*)&smem[VSc + grow * 64 + (((0 + quad) ^ (grow & 7)) * 8)];
            halfx8 bv1 = *(const halfx8*)&smem[VSc + grow * 64 + (((4 + quad) ^ (grow & 7)) * 8)];
            o[gs] = MFMA16(ap0, bv0, o[gs]);
            o[gs] = MFMA16(ap1, bv1, o[gs]);
        }
    }

    float l[4];
#pragma unroll
    for (int r = 0; r < 4; ++r) {
        float ss = l_lane[r];
#pragma unroll
        for (int off = 1; off < 16; off <<= 1)
            ss += __shfl_xor(ss, off, 64);
        l[r] = ss;
    }
#pragma unroll
    for (int gs = 0; gs < 4; ++gs) {
#pragma unroll
        for (int r = 0; r < 4; ++r) {
            int row = row0 + w * 16 + quad * 4 + r;
            out[row * 64 + gs * 16 + l15] = o[gs][r] / l[r];
        }
    }
}

// ---------------------------------------------------------------------------
extern "C" void kernel_launch(void* const* d_in, const int* in_sizes, int n_in,
                              void* d_out, int out_size, void* d_ws, size_t ws_size,
                              hipStream_t stream) {
    const float* x    = (const float*)d_in[0];
    const int*   vlen = (const int*)  d_in[1];
    const float* Wq   = (const float*)d_in[2];
    const float* bq   = (const float*)d_in[3];
    const float* Wk   = (const float*)d_in[4];
    const float* bk   = (const float*)d_in[5];
    const float* Wv   = (const float*)d_in[6];
    const float* bv   = (const float*)d_in[7];
    float* out = (float*)d_out;

    const size_t IMG_SHORTS = (size_t)32 * 16 * 4096;         // 4 MB per image
    const size_t NEED = 3 * IMG_SHORTS * sizeof(unsigned short);  // 12 MB

    if (ws_size >= NEED) {
        unsigned short* qimg = (unsigned short*)d_ws;
        unsigned short* kimg = qimg + IMG_SHORTS;
        unsigned short* vimg = kimg + IMG_SHORTS;
        proj_kernel<<<512, 256, 0, stream>>>(x, Wq, bq, Wk, bk, Wv, bv,
                                             qimg, kimg, vimg);
        attn_kernel<<<512, 256, 0, stream>>>(qimg, kimg, vimg, vlen, out);
    } else {
        fused_attn_fallback<<<512, 256, 0, stream>>>(
            x, Wq, bq, Wk, bk, Wv, bv, vlen, out);
    }
}